// Round 6
// baseline (349.151 us; speedup 1.0000x reference)
//
#include <hip/hip_runtime.h>
#include <hip/hip_fp16.h>
#include <math.h>

// PDELayer: 100 steps of u <- u + alpha(row)*u_xx + beta(col)*u_yy, 48x48
// interior with a FROZEN reflect-pad ring.
//
// R6: R5 structure (lane=(ty,tx) 4x16 owning 12 rows x 3 cols, TWO images
// packed per lane as __half2, DPP16 row shifts + ds_bpermute halos) with one
// targeted change: __launch_bounds__(256, 4) raises the VGPR cap to 128.
// Theory: R1-R5 all showed VGPR_Count below the live set (~90) -> compiler
// was spilling state through AGPRs; v_accvgpr_read/write are VALU insts and
// explain the persistent ~2x gap between ideal issue cycles and measured
// VALUBusy cycles. Grid = 1024 blocks = 4 blocks/CU = exactly 4 waves/EU.
// Also: coefficients computed in-block via LDS (one dispatch total).

#define NTSTEPS 100

typedef __half2 h2;

__device__ __forceinline__ h2 dpp_row_shr1(h2 oldv, h2 x) {
    // lane tx receives lane tx-1 within its 16-lane row; tx==0 keeps oldv
    int r = __builtin_amdgcn_update_dpp(
        __builtin_bit_cast(int, oldv), __builtin_bit_cast(int, x),
        0x111, 0xF, 0xF, false);
    return __builtin_bit_cast(h2, r);
}
__device__ __forceinline__ h2 dpp_row_shl1(h2 oldv, h2 x) {
    // lane tx receives lane tx+1 within its 16-lane row; tx==15 keeps oldv
    int r = __builtin_amdgcn_update_dpp(
        __builtin_bit_cast(int, oldv), __builtin_bit_cast(int, x),
        0x101, 0xF, 0xF, false);
    return __builtin_bit_cast(h2, r);
}
__device__ __forceinline__ h2 bperm(int addr, h2 x) {
    int r = __builtin_amdgcn_ds_bpermute(addr, __builtin_bit_cast(int, x));
    return __builtin_bit_cast(h2, r);
}

__global__ __launch_bounds__(256, 4) void pde_kernel(
    const float* __restrict__ u0,
    const float* __restrict__ pa1, const float* __restrict__ pa2,
    const float* __restrict__ pa3, const float* __restrict__ pb1,
    const float* __restrict__ pb2, const float* __restrict__ pb3,
    float* __restrict__ out)
{
    __shared__ float sh_a[48];   // alpha per original row
    __shared__ float sh_b[48];   // beta per original col

    const int tid  = threadIdx.x;
    const int lane = tid & 63;
    const int wv   = tid >> 6;
    const int pair = blockIdx.x * 4 + wv;   // images 2*pair, 2*pair+1
    const int tx   = lane & 15;
    const int ty   = lane >> 4;
    const int c0   = 3 * tx;
    const int r0   = 12 * ty;

    if (tid < 48) {
        float a1 = fabsf(pa1[0]), a2 = fabsf(pa2[0]), a3 = fabsf(pa3[0]);
        float b1 = fabsf(pb1[0]), b2 = fabsf(pb2[0]), b3 = fabsf(pb3[0]);
        float t = 6.283185307179586f * ((float)tid / 47.0f);
        float s = sinf(t), c = cosf(t);
        sh_a[tid] = 0.1152f * (a1 + a2 * s + a3 * c);  // 0.5*DT/DX^2
        sh_b[tid] = 0.2304f * (b1 + b2 * c + b3 * s);  // DT/DY^2
    }
    __syncthreads();

    const float* __restrict__ srcA = u0 + (size_t)(2 * pair) * 2304;
    const float* __restrict__ srcB = srcA + 2304;

    // coefficients, duplicated into both f16 halves
    h2 a[12], b[3];
    #pragma unroll
    for (int k = 0; k < 12; ++k) a[k] = __half2half2(__float2half(sh_a[r0 + k]));
    #pragma unroll
    for (int c = 0; c < 3; ++c) b[c] = __half2half2(__float2half(sh_b[c0 + c]));
    const h2 neg2 = __floats2half2_rn(-2.0f, -2.0f);

    // state + frozen pads
    h2 u[12][3];
    h2 ep[12];           // tx==0: left pad (orig col 1); tx==15: right pad (col 46)
    h2 tH[3], bH[3];     // vertical halos (frozen for ty==0 / ty==3)

    const int epc = (tx == 15) ? 46 : 1;
    #pragma unroll
    for (int k = 0; k < 12; ++k) {
        #pragma unroll
        for (int c = 0; c < 3; ++c) {
            int o = (r0 + k) * 48 + c0 + c;
            u[k][c] = __floats2half2_rn(srcA[o], srcB[o]);
        }
        int oe = (r0 + k) * 48 + epc;
        ep[k] = __floats2half2_rn(srcA[oe], srcB[oe]);
    }
    {
        const int tor = (ty == 0) ? 1 : (r0 - 1);    // reflect at top
        const int bor = (ty == 3) ? 46 : (r0 + 12);  // reflect at bottom
        #pragma unroll
        for (int c = 0; c < 3; ++c) {
            int ot = tor * 48 + c0 + c, ob = bor * 48 + c0 + c;
            tH[c] = __floats2half2_rn(srcA[ot], srcB[ot]);
            bH[c] = __floats2half2_rn(srcA[ob], srcB[ob]);
        }
    }

    const int upA = ((lane - 16) & 63) << 2;
    const int dnA = ((lane + 16) & 63) << 2;
    const bool notTop = (ty != 0);
    const bool notBot = (ty != 3);

    #pragma unroll 1
    for (int t = 0; t < NTSTEPS; ++t) {
        // refresh live vertical halos from neighbors' OLD state (LDS pipe)
        #pragma unroll
        for (int c = 0; c < 3; ++c) {
            h2 tv = bperm(upA, u[11][c]);
            h2 bv = bperm(dnA, u[0][c]);
            tH[c] = notTop ? tv : tH[c];
            bH[c] = notBot ? bv : bH[c];
        }
        h2 p0 = tH[0], p1 = tH[1], p2 = tH[2];  // old row k-1
        #pragma unroll
        for (int k = 0; k < 12; ++k) {
            const h2 x0 = u[k][0], x1 = u[k][1], x2 = u[k][2];
            const h2 hl = dpp_row_shr1(ep[k], x2);  // left nbr of col0
            const h2 hr = dpp_row_shl1(ep[k], x0);  // right nbr of col2
            const h2 d0 = (k == 11) ? bH[0] : u[k + 1][0];
            const h2 d1 = (k == 11) ? bH[1] : u[k + 1][1];
            const h2 d2 = (k == 11) ? bH[2] : u[k + 1][2];
            const h2 s10 = __hadd2(p0, d0);
            const h2 s11 = __hadd2(p1, d1);
            const h2 s12 = __hadd2(p2, d2);
            const h2 s20 = __hadd2(hl, x1);
            const h2 s21 = __hadd2(x0, x2);
            const h2 s22 = __hadd2(x1, hr);
            const h2 t10 = __hfma2(neg2, x0, s10);  // u_xx
            const h2 t11 = __hfma2(neg2, x1, s11);
            const h2 t12 = __hfma2(neg2, x2, s12);
            const h2 t20 = __hfma2(neg2, x0, s20);  // u_yy
            const h2 t21 = __hfma2(neg2, x1, s21);
            const h2 t22 = __hfma2(neg2, x2, s22);
            const h2 n0 = __hfma2(b[0], t20, __hfma2(a[k], t10, x0));
            const h2 n1 = __hfma2(b[1], t21, __hfma2(a[k], t11, x1));
            const h2 n2 = __hfma2(b[2], t22, __hfma2(a[k], t12, x2));
            p0 = x0; p1 = x1; p2 = x2;
            u[k][0] = n0; u[k][1] = n1; u[k][2] = n2;
        }
    }

    float* __restrict__ dstA = out + (size_t)(2 * pair) * 2304;
    float* __restrict__ dstB = dstA + 2304;
    #pragma unroll
    for (int k = 0; k < 12; ++k) {
        #pragma unroll
        for (int c = 0; c < 3; ++c) {
            int o = (r0 + k) * 48 + c0 + c;
            dstA[o] = __low2float(u[k][c]);
            dstB[o] = __high2float(u[k][c]);
        }
    }
}

extern "C" void kernel_launch(void* const* d_in, const int* in_sizes, int n_in,
                              void* d_out, int out_size, void* d_ws, size_t ws_size,
                              hipStream_t stream) {
    const float* u0 = (const float*)d_in[0];
    pde_kernel<<<1024, 256, 0, stream>>>(
        u0,
        (const float*)d_in[1], (const float*)d_in[2], (const float*)d_in[3],
        (const float*)d_in[4], (const float*)d_in[5], (const float*)d_in[6],
        (float*)d_out);
}